// Round 7
// baseline (337.991 us; speedup 1.0000x reference)
//
#include <hip/hip_runtime.h>

#define N_NODES 4096
#define F_UAV 64
#define NOBS 262400
#define GCN_FLAT (N_NODES * F_UAV)   // 262144
#define HDIM 1024
#define N_ACT 64
#define N_EDGES 65536

typedef float f32x4 __attribute__((ext_vector_type(4)));

// ---- workspace layout (float offsets). [x | deg | y1a | y2a] zeroed by ONE memset.
#define OFF_X    0                           // 262400 floats
#define OFF_DEG  NOBS                        // 4096 ints
#define OFF_Y1A  (OFF_DEG + N_NODES)         // 1024 floats (atomic acc for y1 pre-act)
#define OFF_Y2A  (OFF_Y1A + HDIM)            // 1024 floats (atomic acc for y2 pre-act)
#define OFF_H    (OFF_Y2A + HDIM)            // 262144 floats
#define ZERO_FLOATS (NOBS + N_NODES + 2 * HDIM)

// h = node_x @ gcn_w (4096x64 @ 64x64); blocks <256 also count edge in-degrees
// (deg[] pre-zeroed by the memset).
__global__ __launch_bounds__(256) void k_gcn_h(const float* __restrict__ nx,
                                               const float* __restrict__ w,
                                               const int* __restrict__ dst,
                                               float* __restrict__ h,
                                               int* __restrict__ deg) {
    __shared__ float sw[F_UAV * F_UAV];
    __shared__ float sx4[256];
    int tid = threadIdx.x;
    for (int i = tid; i < F_UAV * F_UAV; i += 256) sw[i] = w[i];
    sx4[tid] = nx[blockIdx.x * 256 + tid];
    if (blockIdx.x < 256) atomicAdd(&deg[dst[blockIdx.x * 256 + tid]], 1);
    __syncthreads();
    int r = tid >> 6, j = tid & 63;
    float acc = 0.f;
#pragma unroll
    for (int k = 0; k < F_UAV; ++k) acc += sx4[r * 64 + k] * sw[k * F_UAV + j];
    h[blockIdx.x * 256 + r * 64 + j] = acc;
}

// fused GCN aggregate into zeroed x:
//   blocks [0,16384): one wave per edge, atomicAdd messages
//   blocks [16384,16640): self-loop term + bias
//   block 16640: obs tail copy
__global__ __launch_bounds__(256) void k_scatter_all(const int* __restrict__ src,
                                                     const int* __restrict__ dst,
                                                     const int* __restrict__ deg,
                                                     const float* __restrict__ h,
                                                     const float* __restrict__ gb,
                                                     const float* __restrict__ obs,
                                                     float* __restrict__ x) {
    int b = blockIdx.x;
    int tid = threadIdx.x;
    if (b < N_EDGES / 4) {
        int e = b * 4 + (tid >> 6);
        int j = tid & 63;
        int s = src[e], d = dst[e];
        float norm = rsqrtf((deg[s] + 1.0f) * (deg[d] + 1.0f));
        atomicAdd(&x[d * 64 + j], h[s * 64 + j] * norm);
    } else if (b < N_EDGES / 4 + 256) {
        int base = (b - N_EDGES / 4) * 1024 + tid * 4;
        int n = base >> 6;
        float dinv2 = 1.0f / (float)(deg[n] + 1);
#pragma unroll
        for (int u = 0; u < 4; ++u) {
            int idx = base + u;
            atomicAdd(&x[idx], h[idx] * dinv2 + gb[idx & 63]);
        }
    } else {
        if (tid < NOBS - GCN_FLAT) x[GCN_FLAT + tid] = obs[GCN_FLAT + tid];
    }
}

// Row-interleaved mat-vec: block b owns rows {b + 2048*i, i<128} (+ tail row
// GCN_FLAT+b for b<256). At any instant the device reads a ~8MB contiguous
// sliding window of W -> DRAM row-buffer locality. Column partials go straight
// into y1a via atomicAdd (y1a pre-zeroed).
__global__ __launch_bounds__(256) void k_mv1(const float* __restrict__ x,
                                             const float* __restrict__ W,
                                             float* __restrict__ y1a) {
    __shared__ float sx[129];
    int tid = threadIdx.x, b = blockIdx.x;
    if (tid < 128) sx[tid] = x[b + 2048 * tid];
    if (tid == 128) sx[128] = (b < 256) ? x[GCN_FLAT + b] : 0.f;
    __syncthreads();
    f32x4 acc = {0.f, 0.f, 0.f, 0.f};
    const f32x4* p = (const f32x4*)W + (size_t)b * (HDIM / 4) + tid;
    const size_t stride = (size_t)2048 * (HDIM / 4);
#pragma unroll 8
    for (int i = 0; i < 128; ++i)
        acc += sx[i] * __builtin_nontemporal_load(&p[(size_t)i * stride]);
    if (b < 256) {
        const f32x4* pt = (const f32x4*)W + (size_t)(GCN_FLAT + b) * (HDIM / 4) + tid;
        acc += sx[128] * __builtin_nontemporal_load(pt);
    }
    atomicAdd(&y1a[4 * tid + 0], acc[0]);
    atomicAdd(&y1a[4 * tid + 1], acc[1]);
    atomicAdd(&y1a[4 * tid + 2], acc[2]);
    atomicAdd(&y1a[4 * tid + 3], acc[3]);
}

// layer 2: 256 blocks x 4 rows. y1 = relu(b1 + y1a) read in-register;
// 4-row matvec vs w2; atomicAdd into y2a.
__global__ __launch_bounds__(256) void k_mv2(const float* __restrict__ y1a,
                                             const float* __restrict__ b1,
                                             const float* __restrict__ w2,
                                             float* __restrict__ y2a) {
    int tid = threadIdx.x, b = blockIdx.x;
    int j0 = 4 * b;
    f32x4 acc = {0.f, 0.f, 0.f, 0.f};
    const f32x4* Wr = (const f32x4*)w2 + (size_t)j0 * (HDIM / 4) + tid;
#pragma unroll
    for (int i = 0; i < 4; ++i) {
        float y = fmaxf(b1[j0 + i] + y1a[j0 + i], 0.f);
        acc += y * Wr[(size_t)i * (HDIM / 4)];
    }
    atomicAdd(&y2a[4 * tid + 0], acc[0]);
    atomicAdd(&y2a[4 * tid + 1], acc[1]);
    atomicAdd(&y2a[4 * tid + 2], acc[2]);
    atomicAdd(&y2a[4 * tid + 3], acc[3]);
}

// fused: y2 = relu(b2 + y2a) then dueling heads. 1 block x 1024.
__global__ __launch_bounds__(1024) void k_heads_f(const float* __restrict__ y2a,
                                                  const float* __restrict__ b2,
                                                  const float* __restrict__ wv,
                                                  const float* __restrict__ bv,
                                                  const float* __restrict__ wa,
                                                  const float* __restrict__ ba,
                                                  float* __restrict__ out) {
    __shared__ float y2s[1024];
    __shared__ float s_adv[16][64];
    __shared__ float s_pv[1024];
    int t = threadIdx.x;
    float y = fmaxf(b2[t] + y2a[t], 0.f);
    y2s[t] = y;
    s_pv[t] = y * wv[t];
    __syncthreads();
    int g = t >> 6, a = t & 63;
    float pa = 0.f;
#pragma unroll 4
    for (int kk = 0; kk < 64; ++kk) pa += y2s[g * 64 + kk] * wa[(g * 64 + kk) * 64 + a];
    s_adv[g][a] = pa;
    __syncthreads();
    if (t < 64) {
        float adv = ba[a];
#pragma unroll
        for (int gg = 0; gg < 16; ++gg) adv += s_adv[gg][a];
        float v = 0.f;
#pragma unroll
        for (int i = 0; i < 16; ++i) v += s_pv[a + 64 * i];
        for (int off = 32; off; off >>= 1) v += __shfl_xor(v, off);
        float m = adv;
        for (int off = 32; off; off >>= 1) m += __shfl_xor(m, off);
        m *= (1.f / 64.f);
        out[a] = (v + bv[0]) + adv - m;
    }
}

extern "C" void kernel_launch(void* const* d_in, const int* in_sizes, int n_in,
                              void* d_out, int out_size, void* d_ws, size_t ws_size,
                              hipStream_t stream) {
    const float* node_x   = (const float*)d_in[0];
    const float* flat_obs = (const float*)d_in[1];
    const float* gcn_w    = (const float*)d_in[2];
    const float* gcn_b    = (const float*)d_in[3];
    const float* w1       = (const float*)d_in[4];
    const float* b1       = (const float*)d_in[5];
    const float* w2       = (const float*)d_in[6];
    const float* b2       = (const float*)d_in[7];
    const float* wv       = (const float*)d_in[8];
    const float* bv       = (const float*)d_in[9];
    const float* wa       = (const float*)d_in[10];
    const float* ba       = (const float*)d_in[11];
    const int*   ei       = (const int*)d_in[12];
    const int* src = ei;
    const int* dst = ei + N_EDGES;

    float* ws   = (float*)d_ws;
    float* x    = ws + OFF_X;
    int*   deg  = (int*)(ws + OFF_DEG);
    float* y1a  = ws + OFF_Y1A;
    float* y2a  = ws + OFF_Y2A;
    float* h    = ws + OFF_H;
    float* out  = (float*)d_out;

    // zero x, deg, y1a, y2a in one shot (adjacent)
    hipMemsetAsync(x, 0, ZERO_FLOATS * sizeof(float), stream);
    k_gcn_h<<<GCN_FLAT / 256, 256, 0, stream>>>(node_x, gcn_w, dst, h, deg);
    k_scatter_all<<<N_EDGES / 4 + 256 + 1, 256, 0, stream>>>(src, dst, deg, h,
                                                             gcn_b, flat_obs, x);

    k_mv1<<<2048, 256, 0, stream>>>(x, w1, y1a);
    k_mv2<<<256, 256, 0, stream>>>(y1a, b1, w2, y2a);
    k_heads_f<<<1, 1024, 0, stream>>>(y2a, b2, wv, bv, wa, ba, out);
}